// Round 4
// baseline (321.059 us; speedup 1.0000x reference)
//
#include <hip/hip_runtime.h>
#include <hip/hip_bf16.h>

// Round 4: NT out-stores, perm-pack bf16 trunc in head, fused agg+pq.
//   S = x@W1[0:128,:], Y' = x@W1[128:256,:]+b1   (k_sy GEMM)
//   k_agg_pq: mean_d = avg relu(S[s]+Y'[d]) -> h=relu(mean@W2+b2) -> [P|Q']
//             stored into SY row's Y-half (cols 256-511). Own-row only: race-free.
//   k_head: z = relu(P[src]+Q'[dst]); logits=z@W4+b4; log_softmax -> out (NT stores)
// ws (bytes):
//   hist/cursor int[50000] @0        (memset)
//   seg  int[50001]        @200064
//   bsum int[256]          @400128
//   ssrc int[800000]       @401152
//   SY   bf16[50000][512]  @3601408
//   w1f @54801408  w2f @54932480  w3f @54998016  w4f @55063552
//   b4p @55075840  flag @55076032     total ~55.1 MB

typedef short bf16x8 __attribute__((ext_vector_type(8)));
typedef float f32x4 __attribute__((ext_vector_type(4)));

#define N_NODES 50000
#define N_EDGES 800000

__device__ __forceinline__ unsigned short f2bf(float f) {
  unsigned u = __builtin_bit_cast(unsigned, f);
  u = u + 0x7fffu + ((u >> 16) & 1u);  // RNE
  return (unsigned short)(u >> 16);
}
__device__ __forceinline__ float bf2f(unsigned short h) {
  unsigned u = ((unsigned)h) << 16;
  return __builtin_bit_cast(float, u);
}
// one v_perm_b32: {bf16(hi), bf16(lo)} by truncation
__device__ __forceinline__ unsigned pack2(float lo, float hi) {
  return __builtin_amdgcn_perm(__builtin_bit_cast(unsigned, hi),
                               __builtin_bit_cast(unsigned, lo), 0x07060302u);
}
__device__ __forceinline__ int ld_src(const int* ei, int m64, int e) {
  return m64 ? ei[2 * e] : ei[e];
}
__device__ __forceinline__ int ld_dst(const int* ei, int m64, int e) {
  return m64 ? ei[2 * N_EDGES + 2 * e] : ei[N_EDGES + e];
}

__global__ void k_prep_frags(const float* __restrict__ W1, const float* __restrict__ W2,
                             const float* __restrict__ W3, const float* __restrict__ W4,
                             const float* __restrict__ b4,
                             unsigned short* __restrict__ w1f, unsigned short* __restrict__ w2f,
                             unsigned short* __restrict__ w3f, unsigned short* __restrict__ w4f,
                             float* __restrict__ b4p, int* __restrict__ flagp,
                             const int* __restrict__ ei) {
  int gid = blockIdx.x * 256 + threadIdx.x;
  if (gid < 65536) {  // w1f: Bcat1[128][512], ct32 ks4
    int i = gid & 7, lane = (gid >> 3) & 63, ks = (gid >> 9) & 3, ct = gid >> 11;
    int k = ks * 32 + (lane >> 4) * 8 + i;
    int c = ct * 16 + (lane & 15);
    float v = (c < 256) ? W1[k * 256 + c] : W1[(128 + k) * 256 + (c - 256)];
    w1f[gid] = f2bf(v);
  } else if (gid < 98304) {  // w2f: W2[256][128], ct8 ks8
    int f = gid - 65536;
    int i = f & 7, lane = (f >> 3) & 63, ks = (f >> 9) & 7, ct = f >> 12;
    int k = ks * 32 + (lane >> 4) * 8 + i;
    int c = ct * 16 + (lane & 15);
    w2f[f] = f2bf(W2[k * 128 + c]);
  } else if (gid < 131072) {  // w3f: Bcat3[128][256], ct16 ks4
    int f = gid - 98304;
    int i = f & 7, lane = (f >> 3) & 63, ks = (f >> 9) & 3, ct = f >> 11;
    int k = ks * 32 + (lane >> 4) * 8 + i;
    int c = ct * 16 + (lane & 15);
    float v = (c < 128) ? W3[k * 128 + c] : W3[(128 + k) * 128 + (c - 128)];
    w3f[f] = f2bf(v);
  } else if (gid < 137216) {  // w4f: W4[128][40->48], ct3 ks4
    int f = gid - 131072;
    int i = f & 7, lane = (f >> 3) & 63, ks = (f >> 9) & 3, ct = f >> 11;
    int k = ks * 32 + (lane >> 4) * 8 + i;
    int c = ct * 16 + (lane & 15);
    w4f[f] = (c < 40) ? f2bf(W4[k * 40 + c]) : (unsigned short)0;
  } else if (gid < 137264) {
    int c = gid - 137216;
    b4p[c] = (c < 40) ? b4[c] : 0.f;
  } else if (gid == 137264) {
    *flagp = (ei[1] == 0 && ei[3] == 0 && ei[5] == 0 && ei[7] == 0) ? 1 : 0;
  }
}

__global__ void k_hist(const int* __restrict__ ei, const int* __restrict__ flagp,
                       int* __restrict__ hist) {
  int e = blockIdx.x * 256 + threadIdx.x;
  atomicAdd(&hist[ld_dst(ei, *flagp, e)], 1);
}

__global__ __launch_bounds__(256) void k_scan_a(const int* __restrict__ hist,
                                                int* __restrict__ bsum) {
  __shared__ int ps[256];
  int t = threadIdx.x, idx = blockIdx.x * 256 + t;
  ps[t] = (idx < N_NODES) ? hist[idx] : 0;
  __syncthreads();
  for (int off = 128; off > 0; off >>= 1) {
    if (t < off) ps[t] += ps[t + off];
    __syncthreads();
  }
  if (t == 0) bsum[blockIdx.x] = ps[0];
}

__global__ __launch_bounds__(256) void k_scan_b(int* __restrict__ bsum, int* __restrict__ seg) {
  __shared__ int ps[256];
  int t = threadIdx.x;
  int v = (t < 196) ? bsum[t] : 0;
  ps[t] = v;
  __syncthreads();
  for (int off = 1; off < 256; off <<= 1) {
    int u = (t >= off) ? ps[t - off] : 0;
    __syncthreads();
    ps[t] += u;
    __syncthreads();
  }
  if (t < 196) bsum[t] = ps[t] - v;  // exclusive
  if (t == 195) seg[N_NODES] = ps[195];
}

__global__ __launch_bounds__(256) void k_scan_c(int* __restrict__ hist,
                                                const int* __restrict__ bsum,
                                                int* __restrict__ seg) {
  __shared__ int ps[256];
  int t = threadIdx.x, idx = blockIdx.x * 256 + t;
  int v = (idx < N_NODES) ? hist[idx] : 0;
  ps[t] = v;
  __syncthreads();
  for (int off = 1; off < 256; off <<= 1) {
    int u = (t >= off) ? ps[t - off] : 0;
    __syncthreads();
    ps[t] += u;
    __syncthreads();
  }
  int run = bsum[blockIdx.x] + ps[t] - v;
  if (idx < N_NODES) {
    seg[idx] = run;
    hist[idx] = run;  // becomes cursor
  }
}

__global__ void k_scatter(const int* __restrict__ ei, const int* __restrict__ flagp,
                          int* __restrict__ cursor, int* __restrict__ ssrc) {
  int e = blockIdx.x * 256 + threadIdx.x;
  int m64 = *flagp;
  int s = ld_src(ei, m64, e), d = ld_dst(ei, m64, e);
  int pos = atomicAdd(&cursor[d], 1);
  ssrc[pos] = s;
}

// SY GEMM: [S|Y'] = x @ [W1top | W1bot], +b1 on Y' cols. 64-row tiles, 8 waves.
__global__ __launch_bounds__(512, 2) void k_sy(const float* __restrict__ x,
                                               const unsigned short* __restrict__ w1f,
                                               const float* __restrict__ b1,
                                               unsigned short* __restrict__ SY) {
  __shared__ __attribute__((aligned(16))) short A[64 * 128];  // 16 KB swizzled (256B rows)
  const int t = threadIdx.x;
  const int nb = blockIdx.x * 64;
  const int nv = min(64, N_NODES - nb);
  const int w = t >> 6, l = t & 63, lr = l & 15, lh = l >> 4;

  bf16x8 B[4][4];
#pragma unroll
  for (int ci = 0; ci < 4; ++ci)
#pragma unroll
    for (int ks = 0; ks < 4; ++ks)
      B[ci][ks] = *(const bf16x8*)(w1f + (((w * 4 + ci) * 4 + ks) * 64 + l) * 8);

#pragma unroll
  for (int j = 0; j < 2; ++j) {
    int c = t + 512 * j;
    int row = c >> 4, ck = c & 15;
    int rr = (row < nv) ? row : 0;
    const float* gp = x + (long)(nb + rr) * 128 + ck * 8;
    float4 v0 = *(const float4*)gp;
    float4 v1 = *(const float4*)(gp + 4);
    bf16x8 o;
    o[0] = (short)f2bf(v0.x); o[1] = (short)f2bf(v0.y);
    o[2] = (short)f2bf(v0.z); o[3] = (short)f2bf(v0.w);
    o[4] = (short)f2bf(v1.x); o[5] = (short)f2bf(v1.y);
    o[6] = (short)f2bf(v1.z); o[7] = (short)f2bf(v1.w);
    int off = (row << 8) + (ck << 4);
    off ^= (row & 7) << 4;
    *(bf16x8*)((char*)A + off) = o;
  }
  __syncthreads();

#pragma unroll
  for (int rt = 0; rt < 4; ++rt) {
    f32x4 acc[4] = {};
#pragma unroll
    for (int ks = 0; ks < 4; ++ks) {
      int row = rt * 16 + lr;
      int off = (row << 8) + (ks << 6) + (lh << 4);
      off ^= (row & 7) << 4;
      bf16x8 a = *(const bf16x8*)((const char*)A + off);
#pragma unroll
      for (int ci = 0; ci < 4; ++ci)
        acc[ci] = __builtin_amdgcn_mfma_f32_16x16x32_bf16(a, B[ci][ks], acc[ci], 0, 0, 0);
    }
#pragma unroll
    for (int ci = 0; ci < 4; ++ci) {
      int col = (w * 4 + ci) * 16 + lr;
      float bb = (col >= 256) ? b1[col - 256] : 0.f;
#pragma unroll
      for (int r = 0; r < 4; ++r) {
        int row = rt * 16 + lh * 4 + r;
        if (row < nv) SY[(long)(nb + row) * 512 + col] = f2bf(acc[ci][r] + bb);
      }
    }
  }
}

// Fused: segment-mean of relu(S[src]+Y'[d]) into LDS -> h=relu(mean@W2+b2) ->
// [P|Q'(+b3)] = h@W3cat, written into own rows' Y-half (cols 256-511).
// 512 threads = 8 waves; wave w aggregates rows w*8..w*8+7 (one node at a time).
__global__ __launch_bounds__(512, 2) void k_agg_pq(
    unsigned short* __restrict__ SY, const int* __restrict__ seg,
    const int* __restrict__ ssrc, const unsigned short* __restrict__ w2f,
    const float* __restrict__ b2, const unsigned short* __restrict__ w3f,
    const float* __restrict__ b3) {
  __shared__ __attribute__((aligned(16))) short M[64 * 256];  // 32 KB (512B rows, swizzled)
  __shared__ __attribute__((aligned(16))) short H[64 * 128];  // 16 KB (256B rows, swizzled)
  const int t = threadIdx.x;
  const int nb = blockIdx.x * 64;
  const int nv = min(64, N_NODES - nb);
  const int w = t >> 6, l = t & 63, lr = l & 15, lh = l >> 4;

#pragma unroll 1
  for (int j = 0; j < 8; ++j) {
    const int row = w * 8 + j;
    const int n = nb + row;
    float a0 = 0.f, a1 = 0.f, a2 = 0.f, a3 = 0.f;
    if (n < N_NODES) {
      const ushort4 yu = *(const ushort4*)(SY + (long)n * 512 + 256 + l * 4);
      const float y0 = bf2f(yu.x), y1 = bf2f(yu.y), y2 = bf2f(yu.z), y3 = bf2f(yu.w);
      const int s0 = seg[n], s1 = seg[n + 1];
      int pos = s0;
      for (; pos + 4 <= s1; pos += 4) {
        int sA = ssrc[pos], sB = ssrc[pos + 1], sC = ssrc[pos + 2], sD = ssrc[pos + 3];
        ushort4 uA = *(const ushort4*)(SY + (long)sA * 512 + l * 4);
        ushort4 uB = *(const ushort4*)(SY + (long)sB * 512 + l * 4);
        ushort4 uC = *(const ushort4*)(SY + (long)sC * 512 + l * 4);
        ushort4 uD = *(const ushort4*)(SY + (long)sD * 512 + l * 4);
        a0 += fmaxf(bf2f(uA.x) + y0, 0.f); a1 += fmaxf(bf2f(uA.y) + y1, 0.f);
        a2 += fmaxf(bf2f(uA.z) + y2, 0.f); a3 += fmaxf(bf2f(uA.w) + y3, 0.f);
        a0 += fmaxf(bf2f(uB.x) + y0, 0.f); a1 += fmaxf(bf2f(uB.y) + y1, 0.f);
        a2 += fmaxf(bf2f(uB.z) + y2, 0.f); a3 += fmaxf(bf2f(uB.w) + y3, 0.f);
        a0 += fmaxf(bf2f(uC.x) + y0, 0.f); a1 += fmaxf(bf2f(uC.y) + y1, 0.f);
        a2 += fmaxf(bf2f(uC.z) + y2, 0.f); a3 += fmaxf(bf2f(uC.w) + y3, 0.f);
        a0 += fmaxf(bf2f(uD.x) + y0, 0.f); a1 += fmaxf(bf2f(uD.y) + y1, 0.f);
        a2 += fmaxf(bf2f(uD.z) + y2, 0.f); a3 += fmaxf(bf2f(uD.w) + y3, 0.f);
      }
      for (; pos < s1; ++pos) {
        int sA = ssrc[pos];
        ushort4 uA = *(const ushort4*)(SY + (long)sA * 512 + l * 4);
        a0 += fmaxf(bf2f(uA.x) + y0, 0.f); a1 += fmaxf(bf2f(uA.y) + y1, 0.f);
        a2 += fmaxf(bf2f(uA.z) + y2, 0.f); a3 += fmaxf(bf2f(uA.w) + y3, 0.f);
      }
      float inv = 1.0f / fmaxf((float)(s1 - s0), 1.0f);
      a0 *= inv; a1 *= inv; a2 *= inv; a3 *= inv;
    }
    ushort4 o;
    o.x = f2bf(a0); o.y = f2bf(a1); o.z = f2bf(a2); o.w = f2bf(a3);
    int off = (row << 9) + (l << 3);
    off ^= (row & 7) << 4;
    *(ushort4*)((char*)M + off) = o;
  }
  __syncthreads();

  // h = relu(mean@W2+b2) -> H. Wave w owns col-tile w (8x16 = 128 cols).
  bf16x8 B2[8];
#pragma unroll
  for (int ks = 0; ks < 8; ++ks)
    B2[ks] = *(const bf16x8*)(w2f + ((w * 8 + ks) * 64 + l) * 8);
  const float b2c = b2[w * 16 + lr];
#pragma unroll
  for (int rt = 0; rt < 4; ++rt) {
    f32x4 acc = {};
#pragma unroll
    for (int ks = 0; ks < 8; ++ks) {
      int row = rt * 16 + lr;
      int off = (row << 9) + (ks << 6) + (lh << 4);
      off ^= (row & 7) << 4;
      bf16x8 a = *(const bf16x8*)((const char*)M + off);
      acc = __builtin_amdgcn_mfma_f32_16x16x32_bf16(a, B2[ks], acc, 0, 0, 0);
    }
    int col = w * 16 + lr;
#pragma unroll
    for (int r = 0; r < 4; ++r) {
      int row = rt * 16 + lh * 4 + r;
      int off = (row << 8) + (col << 1);
      off ^= (row & 7) << 4;
      *(short*)((char*)H + off) = (short)f2bf(fmaxf(acc[r] + b2c, 0.f));
    }
  }
  __syncthreads();

  // [P|Q'] = h@[W3top|W3bot(+b3)] -> SY own-row Y-half. Wave w owns ct w*2, w*2+1.
  bf16x8 B3[2][4];
#pragma unroll
  for (int ci = 0; ci < 2; ++ci)
#pragma unroll
    for (int ks = 0; ks < 4; ++ks)
      B3[ci][ks] = *(const bf16x8*)(w3f + (((w * 2 + ci) * 4 + ks) * 64 + l) * 8);

#pragma unroll
  for (int rt = 0; rt < 4; ++rt) {
    f32x4 acc[2] = {};
#pragma unroll
    for (int ks = 0; ks < 4; ++ks) {
      int row = rt * 16 + lr;
      int off = (row << 8) + (ks << 6) + (lh << 4);
      off ^= (row & 7) << 4;
      bf16x8 a = *(const bf16x8*)((const char*)H + off);
      acc[0] = __builtin_amdgcn_mfma_f32_16x16x32_bf16(a, B3[0][ks], acc[0], 0, 0, 0);
      acc[1] = __builtin_amdgcn_mfma_f32_16x16x32_bf16(a, B3[1][ks], acc[1], 0, 0, 0);
    }
#pragma unroll
    for (int ci = 0; ci < 2; ++ci) {
      int col = (w * 2 + ci) * 16 + lr;
      float bb = (col >= 128) ? b3[col - 128] : 0.f;
#pragma unroll
      for (int r = 0; r < 4; ++r) {
        int row = rt * 16 + lh * 4 + r;
        if (row < nv) SY[(long)(nb + row) * 512 + 256 + col] = f2bf(acc[ci][r] + bb);
      }
    }
  }
}

// Head: z = relu(P[src]+Q'[dst]); logits = z@W4+b4; log_softmax -> out (NT stores).
__global__ __launch_bounds__(256, 2) void k_head(const unsigned short* __restrict__ SY,
                                                 const int* __restrict__ ei,
                                                 const unsigned short* __restrict__ w4f,
                                                 const float* __restrict__ b4p,
                                                 float* __restrict__ out,
                                                 const int* __restrict__ flagp) {
  const int t = threadIdx.x, w = t >> 6, l = t & 63, lr = l & 15, lh = l >> 4;
  const int m64 = *flagp;
  const int eb = blockIdx.x * 64 + w * 16;
  const int el = eb + lr;
  const int sn = ld_src(ei, m64, el);
  const int dn = ld_dst(ei, m64, el);
  const unsigned short* Pp = SY + (long)sn * 512 + 256;
  const unsigned short* Qp = SY + (long)dn * 512 + 384;

  bf16x8 B4[3][4];
#pragma unroll
  for (int ci = 0; ci < 3; ++ci)
#pragma unroll
    for (int ks = 0; ks < 4; ++ks)
      B4[ci][ks] = *(const bf16x8*)(w4f + ((ci * 4 + ks) * 64 + l) * 8);

  f32x4 acc[3] = {};
#pragma unroll
  for (int ks = 0; ks < 4; ++ks) {
    bf16x8 p = *(const bf16x8*)(Pp + ks * 32 + lh * 8);
    bf16x8 q = *(const bf16x8*)(Qp + ks * 32 + lh * 8);
    float f[8];
#pragma unroll
    for (int i = 0; i < 8; ++i)
      f[i] = fmaxf(bf2f((unsigned short)p[i]) + bf2f((unsigned short)q[i]), 0.f);
    int4 a4;
    a4.x = pack2(f[0], f[1]); a4.y = pack2(f[2], f[3]);
    a4.z = pack2(f[4], f[5]); a4.w = pack2(f[6], f[7]);
    bf16x8 a = __builtin_bit_cast(bf16x8, a4);
#pragma unroll
    for (int ci = 0; ci < 3; ++ci)
      acc[ci] = __builtin_amdgcn_mfma_f32_16x16x32_bf16(a, B4[ci][ks], acc[ci], 0, 0, 0);
  }

  float lg0[4], lg1[4], lg2[4];
  const bool val2 = lr < 8;
  const float bb0 = b4p[lr], bb1 = b4p[16 + lr], bb2 = b4p[32 + lr];
#pragma unroll
  for (int r = 0; r < 4; ++r) {
    lg0[r] = acc[0][r] + bb0;
    lg1[r] = acc[1][r] + bb1;
    lg2[r] = acc[2][r] + bb2;
  }
#pragma unroll
  for (int r = 0; r < 4; ++r) {
    float m = fmaxf(lg0[r], lg1[r]);
    if (val2) m = fmaxf(m, lg2[r]);
    m = fmaxf(m, __shfl_xor(m, 1, 64));
    m = fmaxf(m, __shfl_xor(m, 2, 64));
    m = fmaxf(m, __shfl_xor(m, 4, 64));
    m = fmaxf(m, __shfl_xor(m, 8, 64));
    float s = __expf(lg0[r] - m) + __expf(lg1[r] - m) + (val2 ? __expf(lg2[r] - m) : 0.f);
    s += __shfl_xor(s, 1, 64);
    s += __shfl_xor(s, 2, 64);
    s += __shfl_xor(s, 4, 64);
    s += __shfl_xor(s, 8, 64);
    float lse = m + __logf(s);
    long ob = (long)(eb + lh * 4 + r) * 40;
    __builtin_nontemporal_store(lg0[r] - lse, &out[ob + lr]);
    __builtin_nontemporal_store(lg1[r] - lse, &out[ob + 16 + lr]);
    if (val2) __builtin_nontemporal_store(lg2[r] - lse, &out[ob + 32 + lr]);
  }
}

extern "C" void kernel_launch(void* const* d_in, const int* in_sizes, int n_in,
                              void* d_out, int out_size, void* d_ws, size_t ws_size,
                              hipStream_t stream) {
  const float* x = (const float*)d_in[0];
  const int* ei = (const int*)d_in[1];
  const float* W1 = (const float*)d_in[2];
  const float* b1 = (const float*)d_in[3];
  const float* W2 = (const float*)d_in[4];
  const float* b2 = (const float*)d_in[5];
  const float* W3 = (const float*)d_in[6];
  const float* b3 = (const float*)d_in[7];
  const float* W4 = (const float*)d_in[8];
  const float* b4 = (const float*)d_in[9];
  char* ws = (char*)d_ws;
  int* hist = (int*)(ws + 0);
  int* seg = (int*)(ws + 200064);
  int* bsum = (int*)(ws + 400128);
  int* ssrc = (int*)(ws + 401152);
  unsigned short* SY = (unsigned short*)(ws + 3601408);
  unsigned short* w1f = (unsigned short*)(ws + 54801408);
  unsigned short* w2f = (unsigned short*)(ws + 54932480);
  unsigned short* w3f = (unsigned short*)(ws + 54998016);
  unsigned short* w4f = (unsigned short*)(ws + 55063552);
  float* b4p = (float*)(ws + 55075840);
  int* flagp = (int*)(ws + 55076032);
  float* out = (float*)d_out;

  hipMemsetAsync(ws, 0, 200000, stream);  // hist
  k_prep_frags<<<537, 256, 0, stream>>>(W1, W2, W3, W4, b4, w1f, w2f, w3f, w4f, b4p, flagp, ei);
  k_hist<<<3125, 256, 0, stream>>>(ei, flagp, hist);
  k_scan_a<<<196, 256, 0, stream>>>(hist, bsum);
  k_scan_b<<<1, 256, 0, stream>>>(bsum, seg);
  k_scan_c<<<196, 256, 0, stream>>>(hist, bsum, seg);
  k_scatter<<<3125, 256, 0, stream>>>(ei, flagp, hist, ssrc);
  k_sy<<<782, 512, 0, stream>>>(x, w1f, b1, SY);
  k_agg_pq<<<782, 512, 0, stream>>>(SY, seg, ssrc, w2f, b2, w3f, b3);
  k_head<<<12500, 256, 0, stream>>>(SY, ei, w4f, b4p, out, flagp);
}

// Round 5
// 319.581 us; speedup vs baseline: 1.0046x; 1.0046x over previous
//
#include <hip/hip_runtime.h>
#include <hip/hip_bf16.h>

// Round 5: un-fused agg (wave/node, no LDS) + de-interleaved S/Ypr/PQ arrays +
// fewer launches (inline m64 probe, merged scans, fused scatter+sy).
//   S = x@W1[0:128,:]            -> S   [50000][256] bf16
//   Y' = x@W1[128:256,:]+b1      -> Ypr [50000][256] bf16 (mean overwrites in-place)
//   mean_d = avg_e relu(S[src]+Y'[d])    (k_edge_agg, sorted-by-dst segments)
//   h = relu(mean@W2+b2); [P|Q'(+b3)] = h@W3cat -> PQ (aliases dead S)
//   z = relu(P[src]+Q'[dst]); logits=z@W4+b4; log_softmax -> out (NT stores)
// ws (bytes):
//   hist/cursor int[50000] @0        (memset)
//   seg  int[50001]        @200064
//   bsum int[196]          @400128
//   ssrc int[800000]       @401152
//   S/PQ bf16[50000][256]  @3601408
//   Ypr  bf16[50000][256]  @29201408
//   w1f @54801408  w2f @54932480  w3f @54998016  w4f @55063552
//   b4p @55075840     total ~55.1 MB

typedef short bf16x8 __attribute__((ext_vector_type(8)));
typedef float f32x4 __attribute__((ext_vector_type(4)));

#define N_NODES 50000
#define N_EDGES 800000

__device__ __forceinline__ unsigned short f2bf(float f) {
  unsigned u = __builtin_bit_cast(unsigned, f);
  u = u + 0x7fffu + ((u >> 16) & 1u);  // RNE
  return (unsigned short)(u >> 16);
}
__device__ __forceinline__ float bf2f(unsigned short h) {
  unsigned u = ((unsigned)h) << 16;
  return __builtin_bit_cast(float, u);
}
// one v_perm_b32: {bf16(hi), bf16(lo)} by truncation
__device__ __forceinline__ unsigned pack2(float lo, float hi) {
  return __builtin_amdgcn_perm(__builtin_bit_cast(unsigned, hi),
                               __builtin_bit_cast(unsigned, lo), 0x07060302u);
}
// int64-vs-int32 edge_index probe (values < 2^31 -> high words zero)
__device__ __forceinline__ int probe64(const int* ei) {
  return (ei[1] == 0 && ei[3] == 0 && ei[5] == 0 && ei[7] == 0) ? 1 : 0;
}
__device__ __forceinline__ int ld_src(const int* ei, int m64, int e) {
  return m64 ? ei[2 * e] : ei[e];
}
__device__ __forceinline__ int ld_dst(const int* ei, int m64, int e) {
  return m64 ? ei[2 * N_EDGES + 2 * e] : ei[N_EDGES + e];
}

__global__ void k_prep_frags(const float* __restrict__ W1, const float* __restrict__ W2,
                             const float* __restrict__ W3, const float* __restrict__ W4,
                             const float* __restrict__ b4,
                             unsigned short* __restrict__ w1f, unsigned short* __restrict__ w2f,
                             unsigned short* __restrict__ w3f, unsigned short* __restrict__ w4f,
                             float* __restrict__ b4p) {
  int gid = blockIdx.x * 256 + threadIdx.x;
  if (gid < 65536) {  // w1f: Bcat1[128][512], ct32 ks4
    int i = gid & 7, lane = (gid >> 3) & 63, ks = (gid >> 9) & 3, ct = gid >> 11;
    int k = ks * 32 + (lane >> 4) * 8 + i;
    int c = ct * 16 + (lane & 15);
    float v = (c < 256) ? W1[k * 256 + c] : W1[(128 + k) * 256 + (c - 256)];
    w1f[gid] = f2bf(v);
  } else if (gid < 98304) {  // w2f: W2[256][128], ct8 ks8
    int f = gid - 65536;
    int i = f & 7, lane = (f >> 3) & 63, ks = (f >> 9) & 7, ct = f >> 12;
    int k = ks * 32 + (lane >> 4) * 8 + i;
    int c = ct * 16 + (lane & 15);
    w2f[f] = f2bf(W2[k * 128 + c]);
  } else if (gid < 131072) {  // w3f: Bcat3[128][256], ct16 ks4
    int f = gid - 98304;
    int i = f & 7, lane = (f >> 3) & 63, ks = (f >> 9) & 3, ct = f >> 11;
    int k = ks * 32 + (lane >> 4) * 8 + i;
    int c = ct * 16 + (lane & 15);
    float v = (c < 128) ? W3[k * 128 + c] : W3[(128 + k) * 128 + (c - 128)];
    w3f[f] = f2bf(v);
  } else if (gid < 137216) {  // w4f: W4[128][40->48], ct3 ks4
    int f = gid - 131072;
    int i = f & 7, lane = (f >> 3) & 63, ks = (f >> 9) & 3, ct = f >> 11;
    int k = ks * 32 + (lane >> 4) * 8 + i;
    int c = ct * 16 + (lane & 15);
    w4f[f] = (c < 40) ? f2bf(W4[k * 40 + c]) : (unsigned short)0;
  } else if (gid < 137264) {
    int c = gid - 137216;
    b4p[c] = (c < 40) ? b4[c] : 0.f;
  }
}

__global__ void k_hist(const int* __restrict__ ei, int* __restrict__ hist) {
  int e = blockIdx.x * 256 + threadIdx.x;
  atomicAdd(&hist[ld_dst(ei, probe64(ei), e)], 1);
}

__global__ __launch_bounds__(256) void k_scan_a(const int* __restrict__ hist,
                                                int* __restrict__ bsum) {
  __shared__ int ps[256];
  int t = threadIdx.x, idx = blockIdx.x * 256 + t;
  ps[t] = (idx < N_NODES) ? hist[idx] : 0;
  __syncthreads();
  for (int off = 128; off > 0; off >>= 1) {
    if (t < off) ps[t] += ps[t + off];
    __syncthreads();
  }
  if (t == 0) bsum[blockIdx.x] = ps[0];
}

// merged: per-block recompute of bsum prefix + per-element scan of hist chunk.
__global__ __launch_bounds__(256) void k_scan_c(int* __restrict__ hist,
                                                const int* __restrict__ bsum,
                                                int* __restrict__ seg) {
  __shared__ int bs[256];
  __shared__ int ps[256];
  int t = threadIdx.x, idx = blockIdx.x * 256 + t;
  bs[t] = (t < 196) ? bsum[t] : 0;
  __syncthreads();
  for (int off = 1; off < 256; off <<= 1) {
    int u = (t >= off) ? bs[t - off] : 0;
    __syncthreads();
    bs[t] += u;
    __syncthreads();
  }
  const int base = (blockIdx.x == 0) ? 0 : bs[blockIdx.x - 1];
  if (blockIdx.x == 0 && t == 0) seg[N_NODES] = bs[195];
  int v = (idx < N_NODES) ? hist[idx] : 0;
  ps[t] = v;
  __syncthreads();
  for (int off = 1; off < 256; off <<= 1) {
    int u = (t >= off) ? ps[t - off] : 0;
    __syncthreads();
    ps[t] += u;
    __syncthreads();
  }
  int run = base + ps[t] - v;
  if (idx < N_NODES) {
    seg[idx] = run;
    hist[idx] = run;  // becomes cursor
  }
}

// Fused dispatch: blocks [0,1563) scatter; [1563,2345) SY GEMM. 512 threads.
__global__ __launch_bounds__(512, 2) void k_scatter_sy(
    const int* __restrict__ ei, int* __restrict__ cursor, int* __restrict__ ssrc,
    const float* __restrict__ x, const unsigned short* __restrict__ w1f,
    const float* __restrict__ b1, unsigned short* __restrict__ S,
    unsigned short* __restrict__ Ypr) {
  const int t = threadIdx.x;
  if (blockIdx.x < 1563) {
    int e = blockIdx.x * 512 + t;
    if (e < N_EDGES) {
      int m64 = probe64(ei);
      int s = ld_src(ei, m64, e), d = ld_dst(ei, m64, e);
      int pos = atomicAdd(&cursor[d], 1);
      ssrc[pos] = s;
    }
    return;
  }
  __shared__ __attribute__((aligned(16))) short A[64 * 128];  // 16 KB swizzled (256B rows)
  const int nb = (blockIdx.x - 1563) * 64;
  const int nv = min(64, N_NODES - nb);
  const int w = t >> 6, l = t & 63, lr = l & 15, lh = l >> 4;

  bf16x8 B[4][4];
#pragma unroll
  for (int ci = 0; ci < 4; ++ci)
#pragma unroll
    for (int ks = 0; ks < 4; ++ks)
      B[ci][ks] = *(const bf16x8*)(w1f + (((w * 4 + ci) * 4 + ks) * 64 + l) * 8);

#pragma unroll
  for (int j = 0; j < 2; ++j) {
    int c = t + 512 * j;
    int row = c >> 4, ck = c & 15;
    int rr = (row < nv) ? row : 0;
    const float* gp = x + (long)(nb + rr) * 128 + ck * 8;
    float4 v0 = *(const float4*)gp;
    float4 v1 = *(const float4*)(gp + 4);
    bf16x8 o;
    o[0] = (short)f2bf(v0.x); o[1] = (short)f2bf(v0.y);
    o[2] = (short)f2bf(v0.z); o[3] = (short)f2bf(v0.w);
    o[4] = (short)f2bf(v1.x); o[5] = (short)f2bf(v1.y);
    o[6] = (short)f2bf(v1.z); o[7] = (short)f2bf(v1.w);
    int off = (row << 8) + (ck << 4);
    off ^= (row & 7) << 4;
    *(bf16x8*)((char*)A + off) = o;
  }
  __syncthreads();

#pragma unroll
  for (int rt = 0; rt < 4; ++rt) {
    f32x4 acc[4] = {};
#pragma unroll
    for (int ks = 0; ks < 4; ++ks) {
      int row = rt * 16 + lr;
      int off = (row << 8) + (ks << 6) + (lh << 4);
      off ^= (row & 7) << 4;
      bf16x8 a = *(const bf16x8*)((const char*)A + off);
#pragma unroll
      for (int ci = 0; ci < 4; ++ci)
        acc[ci] = __builtin_amdgcn_mfma_f32_16x16x32_bf16(a, B[ci][ks], acc[ci], 0, 0, 0);
    }
#pragma unroll
    for (int ci = 0; ci < 4; ++ci) {
      int col = (w * 4 + ci) * 16 + lr;
#pragma unroll
      for (int r = 0; r < 4; ++r) {
        int row = rt * 16 + lh * 4 + r;
        if (row < nv) {
          if (col < 256) {
            S[(long)(nb + row) * 256 + col] = f2bf(acc[ci][r]);
          } else {
            Ypr[(long)(nb + row) * 256 + (col - 256)] = f2bf(acc[ci][r] + b1[col - 256]);
          }
        }
      }
    }
  }
}

// Segment mean of relu(S[src]+Y'[d]); one wave per node (6250x8=50000), lane owns 4 dims.
__global__ __launch_bounds__(512) void k_edge_agg(const unsigned short* __restrict__ S,
                                                  unsigned short* __restrict__ Ypr,
                                                  const int* __restrict__ seg,
                                                  const int* __restrict__ ssrc) {
  const int t = threadIdx.x, w = t >> 6, l = t & 63;
  const int d = blockIdx.x * 8 + w;
  const int s0 = seg[d], s1 = seg[d + 1];
  unsigned short* Yp = Ypr + (long)d * 256 + l * 4;
  ushort4 yu = *(const ushort4*)Yp;
  const float y0 = bf2f(yu.x), y1 = bf2f(yu.y), y2 = bf2f(yu.z), y3 = bf2f(yu.w);
  float a0 = 0.f, a1 = 0.f, a2 = 0.f, a3 = 0.f;
  int pos = s0;
  for (; pos + 8 <= s1; pos += 8) {
    ushort4 u[8];
#pragma unroll
    for (int j = 0; j < 8; ++j) {
      int s = ssrc[pos + j];
      u[j] = *(const ushort4*)(S + (long)s * 256 + l * 4);
    }
#pragma unroll
    for (int j = 0; j < 8; ++j) {
      a0 += fmaxf(bf2f(u[j].x) + y0, 0.f);
      a1 += fmaxf(bf2f(u[j].y) + y1, 0.f);
      a2 += fmaxf(bf2f(u[j].z) + y2, 0.f);
      a3 += fmaxf(bf2f(u[j].w) + y3, 0.f);
    }
  }
  for (; pos < s1; ++pos) {
    int s = ssrc[pos];
    ushort4 uA = *(const ushort4*)(S + (long)s * 256 + l * 4);
    a0 += fmaxf(bf2f(uA.x) + y0, 0.f);
    a1 += fmaxf(bf2f(uA.y) + y1, 0.f);
    a2 += fmaxf(bf2f(uA.z) + y2, 0.f);
    a3 += fmaxf(bf2f(uA.w) + y3, 0.f);
  }
  float inv = 1.0f / fmaxf((float)(s1 - s0), 1.0f);
  ushort4 o;
  o.x = f2bf(a0 * inv); o.y = f2bf(a1 * inv);
  o.z = f2bf(a2 * inv); o.w = f2bf(a3 * inv);
  *(ushort4*)Yp = o;  // mean overwrites Y' (only this wave touches row d)
}

// h = relu(mean@W2+b2); [P|Q'(+b3)] = h@W3cat -> PQ (aliases dead S). 64 nodes/block.
__global__ __launch_bounds__(256, 2) void k_pq(const unsigned short* __restrict__ Ypr,
                                               unsigned short* __restrict__ PQ,
                                               const unsigned short* __restrict__ w2f,
                                               const float* __restrict__ b2,
                                               const unsigned short* __restrict__ w3f,
                                               const float* __restrict__ b3) {
  __shared__ __attribute__((aligned(16))) short M[64 * 256];  // 32 KB (512B rows, swizzled)
  __shared__ __attribute__((aligned(16))) short H[64 * 128];  // 16 KB (256B rows, swizzled)
  const int t = threadIdx.x;
  const int nb = blockIdx.x * 64;
  const int nv = min(64, N_NODES - nb);
  const int w = t >> 6, l = t & 63, lr = l & 15, lh = l >> 4;

  bf16x8 B2[2][8];
#pragma unroll
  for (int ci = 0; ci < 2; ++ci)
#pragma unroll
    for (int ks = 0; ks < 8; ++ks)
      B2[ci][ks] = *(const bf16x8*)(w2f + (((w * 2 + ci) * 8 + ks) * 64 + l) * 8);

#pragma unroll
  for (int j = 0; j < 8; ++j) {
    int c = t + 256 * j;
    int row = c >> 5, ck = c & 31;
    int rr = (row < nv) ? row : 0;
    int4 v = *(const int4*)(Ypr + (long)(nb + rr) * 256 + ck * 8);
    int off = (row << 9) + (ck << 4);
    off ^= (row & 7) << 4;
    *(int4*)((char*)M + off) = v;
  }
  __syncthreads();

#pragma unroll
  for (int rt = 0; rt < 4; ++rt) {
    f32x4 acc[2] = {};
#pragma unroll
    for (int ks = 0; ks < 8; ++ks) {
      int row = rt * 16 + lr;
      int off = (row << 9) + (ks << 6) + (lh << 4);
      off ^= (row & 7) << 4;
      bf16x8 a = *(const bf16x8*)((const char*)M + off);
      acc[0] = __builtin_amdgcn_mfma_f32_16x16x32_bf16(a, B2[0][ks], acc[0], 0, 0, 0);
      acc[1] = __builtin_amdgcn_mfma_f32_16x16x32_bf16(a, B2[1][ks], acc[1], 0, 0, 0);
    }
#pragma unroll
    for (int ci = 0; ci < 2; ++ci) {
      int col = (w * 2 + ci) * 16 + lr;
      float bb = b2[col];
#pragma unroll
      for (int r = 0; r < 4; ++r) {
        int row = rt * 16 + lh * 4 + r;
        int off = (row << 8) + (col << 1);
        off ^= (row & 7) << 4;
        *(short*)((char*)H + off) = (short)f2bf(fmaxf(acc[ci][r] + bb, 0.f));
      }
    }
  }
  __syncthreads();

  bf16x8 B3[4][4];
#pragma unroll
  for (int ci = 0; ci < 4; ++ci)
#pragma unroll
    for (int ks = 0; ks < 4; ++ks)
      B3[ci][ks] = *(const bf16x8*)(w3f + (((w * 4 + ci) * 4 + ks) * 64 + l) * 8);

#pragma unroll
  for (int rt = 0; rt < 4; ++rt) {
    f32x4 acc[4] = {};
#pragma unroll
    for (int ks = 0; ks < 4; ++ks) {
      int row = rt * 16 + lr;
      int off = (row << 8) + (ks << 6) + (lh << 4);
      off ^= (row & 7) << 4;
      bf16x8 a = *(const bf16x8*)((const char*)H + off);
#pragma unroll
      for (int ci = 0; ci < 4; ++ci)
        acc[ci] = __builtin_amdgcn_mfma_f32_16x16x32_bf16(a, B3[ci][ks], acc[ci], 0, 0, 0);
    }
#pragma unroll
    for (int ci = 0; ci < 4; ++ci) {
      int col = (w * 4 + ci) * 16 + lr;
      float bb = (col >= 128) ? b3[col - 128] : 0.f;
#pragma unroll
      for (int r = 0; r < 4; ++r) {
        int row = rt * 16 + lh * 4 + r;
        if (row < nv) PQ[(long)(nb + row) * 256 + col] = f2bf(acc[ci][r] + bb);
      }
    }
  }
}

// Head: z = relu(P[src]+Q'[dst]); logits = z@W4+b4; log_softmax -> out (NT stores).
__global__ __launch_bounds__(256, 2) void k_head(const unsigned short* __restrict__ PQ,
                                                 const int* __restrict__ ei,
                                                 const unsigned short* __restrict__ w4f,
                                                 const float* __restrict__ b4p,
                                                 float* __restrict__ out) {
  const int t = threadIdx.x, w = t >> 6, l = t & 63, lr = l & 15, lh = l >> 4;
  const int m64 = probe64(ei);
  const int eb = blockIdx.x * 64 + w * 16;
  const int el = eb + lr;
  const int sn = ld_src(ei, m64, el);
  const int dn = ld_dst(ei, m64, el);
  const unsigned short* Pp = PQ + (long)sn * 256;
  const unsigned short* Qp = PQ + (long)dn * 256 + 128;

  bf16x8 B4[3][4];
#pragma unroll
  for (int ci = 0; ci < 3; ++ci)
#pragma unroll
    for (int ks = 0; ks < 4; ++ks)
      B4[ci][ks] = *(const bf16x8*)(w4f + ((ci * 4 + ks) * 64 + l) * 8);

  f32x4 acc[3] = {};
#pragma unroll
  for (int ks = 0; ks < 4; ++ks) {
    bf16x8 p = *(const bf16x8*)(Pp + ks * 32 + lh * 8);
    bf16x8 q = *(const bf16x8*)(Qp + ks * 32 + lh * 8);
    float f[8];
#pragma unroll
    for (int i = 0; i < 8; ++i)
      f[i] = fmaxf(bf2f((unsigned short)p[i]) + bf2f((unsigned short)q[i]), 0.f);
    int4 a4;
    a4.x = pack2(f[0], f[1]); a4.y = pack2(f[2], f[3]);
    a4.z = pack2(f[4], f[5]); a4.w = pack2(f[6], f[7]);
    bf16x8 a = __builtin_bit_cast(bf16x8, a4);
#pragma unroll
    for (int ci = 0; ci < 3; ++ci)
      acc[ci] = __builtin_amdgcn_mfma_f32_16x16x32_bf16(a, B4[ci][ks], acc[ci], 0, 0, 0);
  }

  float lg0[4], lg1[4], lg2[4];
  const bool val2 = lr < 8;
  const float bb0 = b4p[lr], bb1 = b4p[16 + lr], bb2 = b4p[32 + lr];
#pragma unroll
  for (int r = 0; r < 4; ++r) {
    lg0[r] = acc[0][r] + bb0;
    lg1[r] = acc[1][r] + bb1;
    lg2[r] = acc[2][r] + bb2;
  }
#pragma unroll
  for (int r = 0; r < 4; ++r) {
    float m = fmaxf(lg0[r], lg1[r]);
    if (val2) m = fmaxf(m, lg2[r]);
    m = fmaxf(m, __shfl_xor(m, 1, 64));
    m = fmaxf(m, __shfl_xor(m, 2, 64));
    m = fmaxf(m, __shfl_xor(m, 4, 64));
    m = fmaxf(m, __shfl_xor(m, 8, 64));
    float s = __expf(lg0[r] - m) + __expf(lg1[r] - m) + (val2 ? __expf(lg2[r] - m) : 0.f);
    s += __shfl_xor(s, 1, 64);
    s += __shfl_xor(s, 2, 64);
    s += __shfl_xor(s, 4, 64);
    s += __shfl_xor(s, 8, 64);
    float lse = m + __logf(s);
    long ob = (long)(eb + lh * 4 + r) * 40;
    __builtin_nontemporal_store(lg0[r] - lse, &out[ob + lr]);
    __builtin_nontemporal_store(lg1[r] - lse, &out[ob + 16 + lr]);
    if (val2) __builtin_nontemporal_store(lg2[r] - lse, &out[ob + 32 + lr]);
  }
}

extern "C" void kernel_launch(void* const* d_in, const int* in_sizes, int n_in,
                              void* d_out, int out_size, void* d_ws, size_t ws_size,
                              hipStream_t stream) {
  const float* x = (const float*)d_in[0];
  const int* ei = (const int*)d_in[1];
  const float* W1 = (const float*)d_in[2];
  const float* b1 = (const float*)d_in[3];
  const float* W2 = (const float*)d_in[4];
  const float* b2 = (const float*)d_in[5];
  const float* W3 = (const float*)d_in[6];
  const float* b3 = (const float*)d_in[7];
  const float* W4 = (const float*)d_in[8];
  const float* b4 = (const float*)d_in[9];
  char* ws = (char*)d_ws;
  int* hist = (int*)(ws + 0);
  int* seg = (int*)(ws + 200064);
  int* bsum = (int*)(ws + 400128);
  int* ssrc = (int*)(ws + 401152);
  unsigned short* S = (unsigned short*)(ws + 3601408);   // PQ aliases S (dead after agg)
  unsigned short* Ypr = (unsigned short*)(ws + 29201408);
  unsigned short* w1f = (unsigned short*)(ws + 54801408);
  unsigned short* w2f = (unsigned short*)(ws + 54932480);
  unsigned short* w3f = (unsigned short*)(ws + 54998016);
  unsigned short* w4f = (unsigned short*)(ws + 55063552);
  float* b4p = (float*)(ws + 55075840);
  float* out = (float*)d_out;

  hipMemsetAsync(ws, 0, 200000, stream);  // hist
  k_prep_frags<<<537, 256, 0, stream>>>(W1, W2, W3, W4, b4, w1f, w2f, w3f, w4f, b4p);
  k_hist<<<3125, 256, 0, stream>>>(ei, hist);
  k_scan_a<<<196, 256, 0, stream>>>(hist, bsum);
  k_scan_c<<<196, 256, 0, stream>>>(hist, bsum, seg);
  k_scatter_sy<<<2345, 512, 0, stream>>>(ei, hist, ssrc, x, w1f, b1, S, Ypr);
  k_edge_agg<<<6250, 512, 0, stream>>>(S, Ypr, seg, ssrc);
  k_pq<<<782, 256, 0, stream>>>(Ypr, S, w2f, b2, w3f, b3);
  k_head<<<12500, 256, 0, stream>>>(S, ei, w4f, b4p, out);
}

// Round 6
// 286.069 us; speedup vs baseline: 1.1223x; 1.1171x over previous
//
#include <hip/hip_runtime.h>
#include <hip/hip_bf16.h>

// Round 6: single-pass padded-bucket scatter (no hist/scan/sort), standalone GEMMs.
//   S = x@W1[0:128,:]            -> S   [50000][256] bf16
//   Y' = x@W1[128:256,:]+b1      -> Ypr [50000][256] bf16 (mean overwrites in-place)
//   bucket: pos=atomicAdd(cnt[d]); pad[d*128+pos]=src   (order-free, CAP=128)
//   mean_d = avg_i relu(S[pad[d][i]]+Y'[d])   (wave per node, no LDS/barriers)
//   h = relu(mean@W2+b2); [P|Q'(+b3)] = h@W3cat -> PQ (aliases dead S)
//   z = relu(P[src]+Q'[dst]); logits=z@W4+b4; log_softmax -> out (NT stores)
// ws (bytes):
//   cnt  int[50000]          @0          (memset)
//   pad  int[50000*128]      @200064     (25.6 MB)
//   S/PQ bf16[50000][256]    @25800192
//   Ypr  bf16[50000][256]    @51400192
//   w1f @77000192  w2f @77131264  w3f @77196800  w4f @77262336  b4p @77274624
// total ~77.3 MB

typedef short bf16x8 __attribute__((ext_vector_type(8)));
typedef float f32x4 __attribute__((ext_vector_type(4)));

#define N_NODES 50000
#define N_EDGES 800000
#define CAP 128

__device__ __forceinline__ unsigned short f2bf(float f) {
  unsigned u = __builtin_bit_cast(unsigned, f);
  u = u + 0x7fffu + ((u >> 16) & 1u);  // RNE
  return (unsigned short)(u >> 16);
}
__device__ __forceinline__ float bf2f(unsigned short h) {
  unsigned u = ((unsigned)h) << 16;
  return __builtin_bit_cast(float, u);
}
// one v_perm_b32: {bf16(hi), bf16(lo)} by truncation
__device__ __forceinline__ unsigned pack2(float lo, float hi) {
  return __builtin_amdgcn_perm(__builtin_bit_cast(unsigned, hi),
                               __builtin_bit_cast(unsigned, lo), 0x07060302u);
}
// int64-vs-int32 edge_index probe (values < 2^31 -> high words zero)
__device__ __forceinline__ int probe64(const int* ei) {
  return (ei[1] == 0 && ei[3] == 0 && ei[5] == 0 && ei[7] == 0) ? 1 : 0;
}
__device__ __forceinline__ int ld_src(const int* ei, int m64, int e) {
  return m64 ? ei[2 * e] : ei[e];
}
__device__ __forceinline__ int ld_dst(const int* ei, int m64, int e) {
  return m64 ? ei[2 * N_EDGES + 2 * e] : ei[N_EDGES + e];
}

__global__ void k_prep_frags(const float* __restrict__ W1, const float* __restrict__ W2,
                             const float* __restrict__ W3, const float* __restrict__ W4,
                             const float* __restrict__ b4,
                             unsigned short* __restrict__ w1f, unsigned short* __restrict__ w2f,
                             unsigned short* __restrict__ w3f, unsigned short* __restrict__ w4f,
                             float* __restrict__ b4p) {
  int gid = blockIdx.x * 256 + threadIdx.x;
  if (gid < 65536) {  // w1f: Bcat1[128][512], ct32 ks4
    int i = gid & 7, lane = (gid >> 3) & 63, ks = (gid >> 9) & 3, ct = gid >> 11;
    int k = ks * 32 + (lane >> 4) * 8 + i;
    int c = ct * 16 + (lane & 15);
    float v = (c < 256) ? W1[k * 256 + c] : W1[(128 + k) * 256 + (c - 256)];
    w1f[gid] = f2bf(v);
  } else if (gid < 98304) {  // w2f: W2[256][128], ct8 ks8
    int f = gid - 65536;
    int i = f & 7, lane = (f >> 3) & 63, ks = (f >> 9) & 7, ct = f >> 12;
    int k = ks * 32 + (lane >> 4) * 8 + i;
    int c = ct * 16 + (lane & 15);
    w2f[f] = f2bf(W2[k * 128 + c]);
  } else if (gid < 131072) {  // w3f: Bcat3[128][256], ct16 ks4
    int f = gid - 98304;
    int i = f & 7, lane = (f >> 3) & 63, ks = (f >> 9) & 3, ct = f >> 11;
    int k = ks * 32 + (lane >> 4) * 8 + i;
    int c = ct * 16 + (lane & 15);
    float v = (c < 128) ? W3[k * 128 + c] : W3[(128 + k) * 128 + (c - 128)];
    w3f[f] = f2bf(v);
  } else if (gid < 137216) {  // w4f: W4[128][40->48], ct3 ks4
    int f = gid - 131072;
    int i = f & 7, lane = (f >> 3) & 63, ks = (f >> 9) & 3, ct = f >> 11;
    int k = ks * 32 + (lane >> 4) * 8 + i;
    int c = ct * 16 + (lane & 15);
    w4f[f] = (c < 40) ? f2bf(W4[k * 40 + c]) : (unsigned short)0;
  } else if (gid < 137264) {
    int c = gid - 137216;
    b4p[c] = (c < 40) ? b4[c] : 0.f;
  }
}

// One pass: count + bucket-scatter src ids into padded per-node slots.
__global__ void k_count_scatter(const int* __restrict__ ei, int* __restrict__ cnt,
                                int* __restrict__ pad) {
  int e = blockIdx.x * 256 + threadIdx.x;
  int m64 = probe64(ei);
  int s = ld_src(ei, m64, e), d = ld_dst(ei, m64, e);
  int pos = atomicAdd(&cnt[d], 1);
  pad[(d << 7) + pos] = s;
}

// SY GEMM: [S|Y'] = x @ [W1top | W1bot], +b1 on Y' cols. 64-row tiles, 8 waves.
__global__ __launch_bounds__(512, 2) void k_sy(const float* __restrict__ x,
                                               const unsigned short* __restrict__ w1f,
                                               const float* __restrict__ b1,
                                               unsigned short* __restrict__ S,
                                               unsigned short* __restrict__ Ypr) {
  __shared__ __attribute__((aligned(16))) short A[64 * 128];  // 16 KB swizzled (256B rows)
  const int t = threadIdx.x;
  const int nb = blockIdx.x * 64;
  const int nv = min(64, N_NODES - nb);
  const int w = t >> 6, l = t & 63, lr = l & 15, lh = l >> 4;

  bf16x8 B[4][4];
#pragma unroll
  for (int ci = 0; ci < 4; ++ci)
#pragma unroll
    for (int ks = 0; ks < 4; ++ks)
      B[ci][ks] = *(const bf16x8*)(w1f + (((w * 4 + ci) * 4 + ks) * 64 + l) * 8);

#pragma unroll
  for (int j = 0; j < 2; ++j) {
    int c = t + 512 * j;
    int row = c >> 4, ck = c & 15;
    int rr = (row < nv) ? row : 0;
    const float* gp = x + (long)(nb + rr) * 128 + ck * 8;
    float4 v0 = *(const float4*)gp;
    float4 v1 = *(const float4*)(gp + 4);
    bf16x8 o;
    o[0] = (short)f2bf(v0.x); o[1] = (short)f2bf(v0.y);
    o[2] = (short)f2bf(v0.z); o[3] = (short)f2bf(v0.w);
    o[4] = (short)f2bf(v1.x); o[5] = (short)f2bf(v1.y);
    o[6] = (short)f2bf(v1.z); o[7] = (short)f2bf(v1.w);
    int off = (row << 8) + (ck << 4);
    off ^= (row & 7) << 4;
    *(bf16x8*)((char*)A + off) = o;
  }
  __syncthreads();

#pragma unroll
  for (int rt = 0; rt < 4; ++rt) {
    f32x4 acc[4] = {};
#pragma unroll
    for (int ks = 0; ks < 4; ++ks) {
      int row = rt * 16 + lr;
      int off = (row << 8) + (ks << 6) + (lh << 4);
      off ^= (row & 7) << 4;
      bf16x8 a = *(const bf16x8*)((const char*)A + off);
#pragma unroll
      for (int ci = 0; ci < 4; ++ci)
        acc[ci] = __builtin_amdgcn_mfma_f32_16x16x32_bf16(a, B[ci][ks], acc[ci], 0, 0, 0);
    }
#pragma unroll
    for (int ci = 0; ci < 4; ++ci) {
      int col = (w * 4 + ci) * 16 + lr;
#pragma unroll
      for (int r = 0; r < 4; ++r) {
        int row = rt * 16 + lh * 4 + r;
        if (row < nv) {
          if (col < 256) {
            S[(long)(nb + row) * 256 + col] = f2bf(acc[ci][r]);
          } else {
            Ypr[(long)(nb + row) * 256 + (col - 256)] = f2bf(acc[ci][r] + b1[col - 256]);
          }
        }
      }
    }
  }
}

// Mean of relu(S[s]+Y'[d]) over node d's bucket; one wave per node, lane owns 4 dims.
__global__ __launch_bounds__(512) void k_edge_agg(const unsigned short* __restrict__ S,
                                                  unsigned short* __restrict__ Ypr,
                                                  const int* __restrict__ cnt,
                                                  const int* __restrict__ pad) {
  const int t = threadIdx.x, w = t >> 6, l = t & 63;
  const int d = blockIdx.x * 8 + w;
  const int n = cnt[d];
  const int* lp = pad + (d << 7);
  unsigned short* Yp = Ypr + (long)d * 256 + l * 4;
  ushort4 yu = *(const ushort4*)Yp;
  const float y0 = bf2f(yu.x), y1 = bf2f(yu.y), y2 = bf2f(yu.z), y3 = bf2f(yu.w);
  float a0 = 0.f, a1 = 0.f, a2 = 0.f, a3 = 0.f;
  int pos = 0;
  for (; pos + 8 <= n; pos += 8) {
    ushort4 u[8];
#pragma unroll
    for (int j = 0; j < 8; ++j) {
      int s = lp[pos + j];
      u[j] = *(const ushort4*)(S + (long)s * 256 + l * 4);
    }
#pragma unroll
    for (int j = 0; j < 8; ++j) {
      a0 += fmaxf(bf2f(u[j].x) + y0, 0.f);
      a1 += fmaxf(bf2f(u[j].y) + y1, 0.f);
      a2 += fmaxf(bf2f(u[j].z) + y2, 0.f);
      a3 += fmaxf(bf2f(u[j].w) + y3, 0.f);
    }
  }
  for (; pos < n; ++pos) {
    int s = lp[pos];
    ushort4 uA = *(const ushort4*)(S + (long)s * 256 + l * 4);
    a0 += fmaxf(bf2f(uA.x) + y0, 0.f);
    a1 += fmaxf(bf2f(uA.y) + y1, 0.f);
    a2 += fmaxf(bf2f(uA.z) + y2, 0.f);
    a3 += fmaxf(bf2f(uA.w) + y3, 0.f);
  }
  float inv = 1.0f / fmaxf((float)n, 1.0f);
  ushort4 o;
  o.x = f2bf(a0 * inv); o.y = f2bf(a1 * inv);
  o.z = f2bf(a2 * inv); o.w = f2bf(a3 * inv);
  *(ushort4*)Yp = o;  // mean overwrites Y' (only this wave touches row d)
}

// h = relu(mean@W2+b2); [P|Q'(+b3)] = h@W3cat -> PQ (aliases dead S). 64 nodes/block.
__global__ __launch_bounds__(256, 2) void k_pq(const unsigned short* __restrict__ Ypr,
                                               unsigned short* __restrict__ PQ,
                                               const unsigned short* __restrict__ w2f,
                                               const float* __restrict__ b2,
                                               const unsigned short* __restrict__ w3f,
                                               const float* __restrict__ b3) {
  __shared__ __attribute__((aligned(16))) short M[64 * 256];  // 32 KB (512B rows, swizzled)
  __shared__ __attribute__((aligned(16))) short H[64 * 128];  // 16 KB (256B rows, swizzled)
  const int t = threadIdx.x;
  const int nb = blockIdx.x * 64;
  const int nv = min(64, N_NODES - nb);
  const int w = t >> 6, l = t & 63, lr = l & 15, lh = l >> 4;

  bf16x8 B2[2][8];
#pragma unroll
  for (int ci = 0; ci < 2; ++ci)
#pragma unroll
    for (int ks = 0; ks < 8; ++ks)
      B2[ci][ks] = *(const bf16x8*)(w2f + (((w * 2 + ci) * 8 + ks) * 64 + l) * 8);

#pragma unroll
  for (int j = 0; j < 8; ++j) {
    int c = t + 256 * j;
    int row = c >> 5, ck = c & 31;
    int rr = (row < nv) ? row : 0;
    int4 v = *(const int4*)(Ypr + (long)(nb + rr) * 256 + ck * 8);
    int off = (row << 9) + (ck << 4);
    off ^= (row & 7) << 4;
    *(int4*)((char*)M + off) = v;
  }
  __syncthreads();

#pragma unroll
  for (int rt = 0; rt < 4; ++rt) {
    f32x4 acc[2] = {};
#pragma unroll
    for (int ks = 0; ks < 8; ++ks) {
      int row = rt * 16 + lr;
      int off = (row << 9) + (ks << 6) + (lh << 4);
      off ^= (row & 7) << 4;
      bf16x8 a = *(const bf16x8*)((const char*)M + off);
      acc[0] = __builtin_amdgcn_mfma_f32_16x16x32_bf16(a, B2[0][ks], acc[0], 0, 0, 0);
      acc[1] = __builtin_amdgcn_mfma_f32_16x16x32_bf16(a, B2[1][ks], acc[1], 0, 0, 0);
    }
#pragma unroll
    for (int ci = 0; ci < 2; ++ci) {
      int col = (w * 2 + ci) * 16 + lr;
      float bb = b2[col];
#pragma unroll
      for (int r = 0; r < 4; ++r) {
        int row = rt * 16 + lh * 4 + r;
        int off = (row << 8) + (col << 1);
        off ^= (row & 7) << 4;
        *(short*)((char*)H + off) = (short)f2bf(fmaxf(acc[ci][r] + bb, 0.f));
      }
    }
  }
  __syncthreads();

  bf16x8 B3[4][4];
#pragma unroll
  for (int ci = 0; ci < 4; ++ci)
#pragma unroll
    for (int ks = 0; ks < 4; ++ks)
      B3[ci][ks] = *(const bf16x8*)(w3f + (((w * 4 + ci) * 4 + ks) * 64 + l) * 8);

#pragma unroll
  for (int rt = 0; rt < 4; ++rt) {
    f32x4 acc[4] = {};
#pragma unroll
    for (int ks = 0; ks < 4; ++ks) {
      int row = rt * 16 + lr;
      int off = (row << 8) + (ks << 6) + (lh << 4);
      off ^= (row & 7) << 4;
      bf16x8 a = *(const bf16x8*)((const char*)H + off);
#pragma unroll
      for (int ci = 0; ci < 4; ++ci)
        acc[ci] = __builtin_amdgcn_mfma_f32_16x16x32_bf16(a, B3[ci][ks], acc[ci], 0, 0, 0);
    }
#pragma unroll
    for (int ci = 0; ci < 4; ++ci) {
      int col = (w * 4 + ci) * 16 + lr;
      float bb = (col >= 128) ? b3[col - 128] : 0.f;
#pragma unroll
      for (int r = 0; r < 4; ++r) {
        int row = rt * 16 + lh * 4 + r;
        if (row < nv) PQ[(long)(nb + row) * 256 + col] = f2bf(acc[ci][r] + bb);
      }
    }
  }
}

// Head: z = relu(P[src]+Q'[dst]); logits = z@W4+b4; log_softmax -> out (NT stores).
__global__ __launch_bounds__(256, 2) void k_head(const unsigned short* __restrict__ PQ,
                                                 const int* __restrict__ ei,
                                                 const unsigned short* __restrict__ w4f,
                                                 const float* __restrict__ b4p,
                                                 float* __restrict__ out) {
  const int t = threadIdx.x, w = t >> 6, l = t & 63, lr = l & 15, lh = l >> 4;
  const int m64 = probe64(ei);
  const int eb = blockIdx.x * 64 + w * 16;
  const int el = eb + lr;
  const int sn = ld_src(ei, m64, el);
  const int dn = ld_dst(ei, m64, el);
  const unsigned short* Pp = PQ + (long)sn * 256;
  const unsigned short* Qp = PQ + (long)dn * 256 + 128;

  bf16x8 B4[3][4];
#pragma unroll
  for (int ci = 0; ci < 3; ++ci)
#pragma unroll
    for (int ks = 0; ks < 4; ++ks)
      B4[ci][ks] = *(const bf16x8*)(w4f + ((ci * 4 + ks) * 64 + l) * 8);

  f32x4 acc[3] = {};
#pragma unroll
  for (int ks = 0; ks < 4; ++ks) {
    bf16x8 p = *(const bf16x8*)(Pp + ks * 32 + lh * 8);
    bf16x8 q = *(const bf16x8*)(Qp + ks * 32 + lh * 8);
    float f[8];
#pragma unroll
    for (int i = 0; i < 8; ++i)
      f[i] = fmaxf(bf2f((unsigned short)p[i]) + bf2f((unsigned short)q[i]), 0.f);
    int4 a4;
    a4.x = pack2(f[0], f[1]); a4.y = pack2(f[2], f[3]);
    a4.z = pack2(f[4], f[5]); a4.w = pack2(f[6], f[7]);
    bf16x8 a = __builtin_bit_cast(bf16x8, a4);
#pragma unroll
    for (int ci = 0; ci < 3; ++ci)
      acc[ci] = __builtin_amdgcn_mfma_f32_16x16x32_bf16(a, B4[ci][ks], acc[ci], 0, 0, 0);
  }

  float lg0[4], lg1[4], lg2[4];
  const bool val2 = lr < 8;
  const float bb0 = b4p[lr], bb1 = b4p[16 + lr], bb2 = b4p[32 + lr];
#pragma unroll
  for (int r = 0; r < 4; ++r) {
    lg0[r] = acc[0][r] + bb0;
    lg1[r] = acc[1][r] + bb1;
    lg2[r] = acc[2][r] + bb2;
  }
#pragma unroll
  for (int r = 0; r < 4; ++r) {
    float m = fmaxf(lg0[r], lg1[r]);
    if (val2) m = fmaxf(m, lg2[r]);
    m = fmaxf(m, __shfl_xor(m, 1, 64));
    m = fmaxf(m, __shfl_xor(m, 2, 64));
    m = fmaxf(m, __shfl_xor(m, 4, 64));
    m = fmaxf(m, __shfl_xor(m, 8, 64));
    float s = __expf(lg0[r] - m) + __expf(lg1[r] - m) + (val2 ? __expf(lg2[r] - m) : 0.f);
    s += __shfl_xor(s, 1, 64);
    s += __shfl_xor(s, 2, 64);
    s += __shfl_xor(s, 4, 64);
    s += __shfl_xor(s, 8, 64);
    float lse = m + __logf(s);
    long ob = (long)(eb + lh * 4 + r) * 40;
    __builtin_nontemporal_store(lg0[r] - lse, &out[ob + lr]);
    __builtin_nontemporal_store(lg1[r] - lse, &out[ob + 16 + lr]);
    if (val2) __builtin_nontemporal_store(lg2[r] - lse, &out[ob + 32 + lr]);
  }
}

extern "C" void kernel_launch(void* const* d_in, const int* in_sizes, int n_in,
                              void* d_out, int out_size, void* d_ws, size_t ws_size,
                              hipStream_t stream) {
  const float* x = (const float*)d_in[0];
  const int* ei = (const int*)d_in[1];
  const float* W1 = (const float*)d_in[2];
  const float* b1 = (const float*)d_in[3];
  const float* W2 = (const float*)d_in[4];
  const float* b2 = (const float*)d_in[5];
  const float* W3 = (const float*)d_in[6];
  const float* b3 = (const float*)d_in[7];
  const float* W4 = (const float*)d_in[8];
  const float* b4 = (const float*)d_in[9];
  char* ws = (char*)d_ws;
  int* cnt = (int*)(ws + 0);
  int* pad = (int*)(ws + 200064);
  unsigned short* S = (unsigned short*)(ws + 25800192);  // PQ aliases S (dead after agg)
  unsigned short* Ypr = (unsigned short*)(ws + 51400192);
  unsigned short* w1f = (unsigned short*)(ws + 77000192);
  unsigned short* w2f = (unsigned short*)(ws + 77131264);
  unsigned short* w3f = (unsigned short*)(ws + 77196800);
  unsigned short* w4f = (unsigned short*)(ws + 77262336);
  float* b4p = (float*)(ws + 77274624);
  float* out = (float*)d_out;

  hipMemsetAsync(ws, 0, 200064, stream);  // cnt
  k_prep_frags<<<537, 256, 0, stream>>>(W1, W2, W3, W4, b4, w1f, w2f, w3f, w4f, b4p);
  k_count_scatter<<<3125, 256, 0, stream>>>(ei, cnt, pad);
  k_sy<<<782, 512, 0, stream>>>(x, w1f, b1, S, Ypr);
  k_edge_agg<<<6250, 512, 0, stream>>>(S, Ypr, cnt, pad);
  k_pq<<<782, 256, 0, stream>>>(Ypr, S, w2f, b2, w3f, b3);
  k_head<<<12500, 256, 0, stream>>>(S, ei, w4f, b4p, out);
}

// Round 8
// 274.129 us; speedup vs baseline: 1.1712x; 1.0436x over previous
//
#include <hip/hip_runtime.h>
#include <hip/hip_bf16.h>

// Round 8: fix r7 compile (no __hip_bfloat162 bit_cast); head does 32 edges/wave
// (2 independent gather+MFMA chains for MLP); plain out stores; u32 unpack in agg.
//   S = x@W1[0:128,:]            -> S   [50000][256] bf16
//   Y' = x@W1[128:256,:]+b1      -> Ypr [50000][256] bf16 (mean overwrites in-place)
//   bucket: pos=atomicAdd(cnt[d]); pad[d*128+pos]=(ushort)src
//   mean_d = avg_i relu(S[pad[d][i]]+Y'[d])   (wave per node, no LDS/barriers)
//   h = relu(mean@W2+b2); [P|Q'(+b3)] = h@W3cat -> PQ (aliases dead S)
//   z = relu(P[src]+Q'[dst]); logits=z@W4+b4; log_softmax -> out
// ws (bytes):
//   cnt  int[50000]            @0          (memset)
//   pad  ushort[50000*128]     @200064     (12.8 MB)
//   S/PQ bf16[50000][256]      @13000192
//   Ypr  bf16[50000][256]      @38600192
//   w1f @64200192  w2f @64331264  w3f @64396800  w4f @64462336  b4p @64474624
// total ~64.5 MB

typedef short bf16x8 __attribute__((ext_vector_type(8)));
typedef float f32x4 __attribute__((ext_vector_type(4)));

#define N_NODES 50000
#define N_EDGES 800000

__device__ __forceinline__ unsigned short f2bf(float f) {
  unsigned u = __builtin_bit_cast(unsigned, f);
  u = u + 0x7fffu + ((u >> 16) & 1u);  // RNE
  return (unsigned short)(u >> 16);
}
__device__ __forceinline__ float lo_f(unsigned u) {
  return __builtin_bit_cast(float, u << 16);
}
__device__ __forceinline__ float hi_f(unsigned u) {
  return __builtin_bit_cast(float, u & 0xffff0000u);
}
// one v_perm_b32: {bf16(hi), bf16(lo)} by truncation
__device__ __forceinline__ unsigned pack2(float lo, float hi) {
  return __builtin_amdgcn_perm(__builtin_bit_cast(unsigned, hi),
                               __builtin_bit_cast(unsigned, lo), 0x07060302u);
}
// int64-vs-int32 edge_index probe (values < 2^31 -> high words zero)
__device__ __forceinline__ int probe64(const int* ei) {
  return (ei[1] == 0 && ei[3] == 0 && ei[5] == 0 && ei[7] == 0) ? 1 : 0;
}
__device__ __forceinline__ int ld_src(const int* ei, int m64, int e) {
  return m64 ? ei[2 * e] : ei[e];
}
__device__ __forceinline__ int ld_dst(const int* ei, int m64, int e) {
  return m64 ? ei[2 * N_EDGES + 2 * e] : ei[N_EDGES + e];
}

__global__ void k_prep_frags(const float* __restrict__ W1, const float* __restrict__ W2,
                             const float* __restrict__ W3, const float* __restrict__ W4,
                             const float* __restrict__ b4,
                             unsigned short* __restrict__ w1f, unsigned short* __restrict__ w2f,
                             unsigned short* __restrict__ w3f, unsigned short* __restrict__ w4f,
                             float* __restrict__ b4p) {
  int gid = blockIdx.x * 256 + threadIdx.x;
  if (gid < 65536) {  // w1f: Bcat1[128][512], ct32 ks4
    int i = gid & 7, lane = (gid >> 3) & 63, ks = (gid >> 9) & 3, ct = gid >> 11;
    int k = ks * 32 + (lane >> 4) * 8 + i;
    int c = ct * 16 + (lane & 15);
    float v = (c < 256) ? W1[k * 256 + c] : W1[(128 + k) * 256 + (c - 256)];
    w1f[gid] = f2bf(v);
  } else if (gid < 98304) {  // w2f: W2[256][128], ct8 ks8
    int f = gid - 65536;
    int i = f & 7, lane = (f >> 3) & 63, ks = (f >> 9) & 7, ct = f >> 12;
    int k = ks * 32 + (lane >> 4) * 8 + i;
    int c = ct * 16 + (lane & 15);
    w2f[f] = f2bf(W2[k * 128 + c]);
  } else if (gid < 131072) {  // w3f: Bcat3[128][256], ct16 ks4
    int f = gid - 98304;
    int i = f & 7, lane = (f >> 3) & 63, ks = (f >> 9) & 3, ct = f >> 11;
    int k = ks * 32 + (lane >> 4) * 8 + i;
    int c = ct * 16 + (lane & 15);
    float v = (c < 128) ? W3[k * 128 + c] : W3[(128 + k) * 128 + (c - 128)];
    w3f[f] = f2bf(v);
  } else if (gid < 137216) {  // w4f: W4[128][40->48], ct3 ks4
    int f = gid - 131072;
    int i = f & 7, lane = (f >> 3) & 63, ks = (f >> 9) & 3, ct = f >> 11;
    int k = ks * 32 + (lane >> 4) * 8 + i;
    int c = ct * 16 + (lane & 15);
    w4f[f] = (c < 40) ? f2bf(W4[k * 40 + c]) : (unsigned short)0;
  } else if (gid < 137264) {
    int c = gid - 137216;
    b4p[c] = (c < 40) ? b4[c] : 0.f;
  }
}

// One pass: count + bucket-scatter src ids (ushort) into padded per-node slots.
__global__ void k_count_scatter(const int* __restrict__ ei, int* __restrict__ cnt,
                                unsigned short* __restrict__ pad) {
  int e = blockIdx.x * 256 + threadIdx.x;
  int m64 = probe64(ei);
  int s = ld_src(ei, m64, e), d = ld_dst(ei, m64, e);
  int pos = atomicAdd(&cnt[d], 1);
  pad[(d << 7) + pos] = (unsigned short)s;
}

// SY GEMM: [S|Y'] = x @ [W1top | W1bot], +b1 on Y' cols. 64-row tiles, 8 waves.
__global__ __launch_bounds__(512, 2) void k_sy(const float* __restrict__ x,
                                               const unsigned short* __restrict__ w1f,
                                               const float* __restrict__ b1,
                                               unsigned short* __restrict__ S,
                                               unsigned short* __restrict__ Ypr) {
  __shared__ __attribute__((aligned(16))) short A[64 * 128];  // 16 KB swizzled (256B rows)
  const int t = threadIdx.x;
  const int nb = blockIdx.x * 64;
  const int nv = min(64, N_NODES - nb);
  const int w = t >> 6, l = t & 63, lr = l & 15, lh = l >> 4;

  bf16x8 B[4][4];
#pragma unroll
  for (int ci = 0; ci < 4; ++ci)
#pragma unroll
    for (int ks = 0; ks < 4; ++ks)
      B[ci][ks] = *(const bf16x8*)(w1f + (((w * 4 + ci) * 4 + ks) * 64 + l) * 8);

#pragma unroll
  for (int j = 0; j < 2; ++j) {
    int c = t + 512 * j;
    int row = c >> 4, ck = c & 15;
    int rr = (row < nv) ? row : 0;
    const float* gp = x + (long)(nb + rr) * 128 + ck * 8;
    float4 v0 = *(const float4*)gp;
    float4 v1 = *(const float4*)(gp + 4);
    bf16x8 o;
    o[0] = (short)f2bf(v0.x); o[1] = (short)f2bf(v0.y);
    o[2] = (short)f2bf(v0.z); o[3] = (short)f2bf(v0.w);
    o[4] = (short)f2bf(v1.x); o[5] = (short)f2bf(v1.y);
    o[6] = (short)f2bf(v1.z); o[7] = (short)f2bf(v1.w);
    int off = (row << 8) + (ck << 4);
    off ^= (row & 7) << 4;
    *(bf16x8*)((char*)A + off) = o;
  }
  __syncthreads();

#pragma unroll
  for (int rt = 0; rt < 4; ++rt) {
    f32x4 acc[4] = {};
#pragma unroll
    for (int ks = 0; ks < 4; ++ks) {
      int row = rt * 16 + lr;
      int off = (row << 8) + (ks << 6) + (lh << 4);
      off ^= (row & 7) << 4;
      bf16x8 a = *(const bf16x8*)((const char*)A + off);
#pragma unroll
      for (int ci = 0; ci < 4; ++ci)
        acc[ci] = __builtin_amdgcn_mfma_f32_16x16x32_bf16(a, B[ci][ks], acc[ci], 0, 0, 0);
    }
#pragma unroll
    for (int ci = 0; ci < 4; ++ci) {
      int col = (w * 4 + ci) * 16 + lr;
#pragma unroll
      for (int r = 0; r < 4; ++r) {
        int row = rt * 16 + lh * 4 + r;
        if (row < nv) {
          if (col < 256) {
            S[(long)(nb + row) * 256 + col] = f2bf(acc[ci][r]);
          } else {
            Ypr[(long)(nb + row) * 256 + (col - 256)] = f2bf(acc[ci][r] + b1[col - 256]);
          }
        }
      }
    }
  }
}

// Mean of relu(S[s]+Y'[d]) over node d's bucket; one wave per node, lane owns 4 dims.
__global__ __launch_bounds__(512) void k_edge_agg(const unsigned short* __restrict__ S,
                                                  unsigned short* __restrict__ Ypr,
                                                  const int* __restrict__ cnt,
                                                  const unsigned short* __restrict__ pad) {
  const int t = threadIdx.x, w = t >> 6, l = t & 63;
  const int d = blockIdx.x * 8 + w;
  const int n = cnt[d];
  const unsigned short* lp = pad + (d << 7);
  unsigned short* Yp = Ypr + (long)d * 256 + l * 4;
  const uint2 yu = *(const uint2*)Yp;
  const float y0 = lo_f(yu.x), y1 = hi_f(yu.x), y2 = lo_f(yu.y), y3 = hi_f(yu.y);
  float a0 = 0.f, a1 = 0.f, a2 = 0.f, a3 = 0.f;
  int pos = 0;
  for (; pos + 8 <= n; pos += 8) {
    uint2 u[8];
#pragma unroll
    for (int j = 0; j < 8; ++j) {
      int s = (int)lp[pos + j];
      u[j] = *(const uint2*)(S + (long)s * 256 + l * 4);
    }
#pragma unroll
    for (int j = 0; j < 8; ++j) {
      a0 += fmaxf(lo_f(u[j].x) + y0, 0.f);
      a1 += fmaxf(hi_f(u[j].x) + y1, 0.f);
      a2 += fmaxf(lo_f(u[j].y) + y2, 0.f);
      a3 += fmaxf(hi_f(u[j].y) + y3, 0.f);
    }
  }
  for (; pos < n; ++pos) {
    int s = (int)lp[pos];
    uint2 uA = *(const uint2*)(S + (long)s * 256 + l * 4);
    a0 += fmaxf(lo_f(uA.x) + y0, 0.f);
    a1 += fmaxf(hi_f(uA.x) + y1, 0.f);
    a2 += fmaxf(lo_f(uA.y) + y2, 0.f);
    a3 += fmaxf(hi_f(uA.y) + y3, 0.f);
  }
  float inv = 1.0f / fmaxf((float)n, 1.0f);
  ushort4 o;
  o.x = f2bf(a0 * inv); o.y = f2bf(a1 * inv);
  o.z = f2bf(a2 * inv); o.w = f2bf(a3 * inv);
  *(ushort4*)Yp = o;  // mean overwrites Y' (only this wave touches row d)
}

// h = relu(mean@W2+b2); [P|Q'(+b3)] = h@W3cat -> PQ (aliases dead S). 64 nodes/block.
__global__ __launch_bounds__(256, 2) void k_pq(const unsigned short* __restrict__ Ypr,
                                               unsigned short* __restrict__ PQ,
                                               const unsigned short* __restrict__ w2f,
                                               const float* __restrict__ b2,
                                               const unsigned short* __restrict__ w3f,
                                               const float* __restrict__ b3) {
  __shared__ __attribute__((aligned(16))) short M[64 * 256];  // 32 KB (512B rows, swizzled)
  __shared__ __attribute__((aligned(16))) short H[64 * 128];  // 16 KB (256B rows, swizzled)
  const int t = threadIdx.x;
  const int nb = blockIdx.x * 64;
  const int nv = min(64, N_NODES - nb);
  const int w = t >> 6, l = t & 63, lr = l & 15, lh = l >> 4;

  bf16x8 B2[2][8];
#pragma unroll
  for (int ci = 0; ci < 2; ++ci)
#pragma unroll
    for (int ks = 0; ks < 8; ++ks)
      B2[ci][ks] = *(const bf16x8*)(w2f + (((w * 2 + ci) * 8 + ks) * 64 + l) * 8);

#pragma unroll
  for (int j = 0; j < 8; ++j) {
    int c = t + 256 * j;
    int row = c >> 5, ck = c & 31;
    int rr = (row < nv) ? row : 0;
    int4 v = *(const int4*)(Ypr + (long)(nb + rr) * 256 + ck * 8);
    int off = (row << 9) + (ck << 4);
    off ^= (row & 7) << 4;
    *(int4*)((char*)M + off) = v;
  }
  __syncthreads();

#pragma unroll
  for (int rt = 0; rt < 4; ++rt) {
    f32x4 acc[2] = {};
#pragma unroll
    for (int ks = 0; ks < 8; ++ks) {
      int row = rt * 16 + lr;
      int off = (row << 9) + (ks << 6) + (lh << 4);
      off ^= (row & 7) << 4;
      bf16x8 a = *(const bf16x8*)((const char*)M + off);
      acc[0] = __builtin_amdgcn_mfma_f32_16x16x32_bf16(a, B2[0][ks], acc[0], 0, 0, 0);
      acc[1] = __builtin_amdgcn_mfma_f32_16x16x32_bf16(a, B2[1][ks], acc[1], 0, 0, 0);
    }
#pragma unroll
    for (int ci = 0; ci < 2; ++ci) {
      int col = (w * 2 + ci) * 16 + lr;
      float bb = b2[col];
#pragma unroll
      for (int r = 0; r < 4; ++r) {
        int row = rt * 16 + lh * 4 + r;
        int off = (row << 8) + (col << 1);
        off ^= (row & 7) << 4;
        *(short*)((char*)H + off) = (short)f2bf(fmaxf(acc[ci][r] + bb, 0.f));
      }
    }
  }
  __syncthreads();

  bf16x8 B3[4][4];
#pragma unroll
  for (int ci = 0; ci < 4; ++ci)
#pragma unroll
    for (int ks = 0; ks < 4; ++ks)
      B3[ci][ks] = *(const bf16x8*)(w3f + (((w * 4 + ci) * 4 + ks) * 64 + l) * 8);

#pragma unroll
  for (int rt = 0; rt < 4; ++rt) {
    f32x4 acc[4] = {};
#pragma unroll
    for (int ks = 0; ks < 4; ++ks) {
      int row = rt * 16 + lr;
      int off = (row << 8) + (ks << 6) + (lh << 4);
      off ^= (row & 7) << 4;
      bf16x8 a = *(const bf16x8*)((const char*)H + off);
#pragma unroll
      for (int ci = 0; ci < 4; ++ci)
        acc[ci] = __builtin_amdgcn_mfma_f32_16x16x32_bf16(a, B3[ci][ks], acc[ci], 0, 0, 0);
    }
#pragma unroll
    for (int ci = 0; ci < 4; ++ci) {
      int col = (w * 4 + ci) * 16 + lr;
      float bb = (col >= 128) ? b3[col - 128] : 0.f;
#pragma unroll
      for (int r = 0; r < 4; ++r) {
        int row = rt * 16 + lh * 4 + r;
        if (row < nv) PQ[(long)(nb + row) * 256 + col] = f2bf(acc[ci][r] + bb);
      }
    }
  }
}

// Head: 32 edges/wave (two independent 16-edge chains A/B for MLP).
// z = relu(P[src]+Q'[dst]); logits = z@W4+b4; log_softmax -> out.
__global__ __launch_bounds__(256) void k_head(const unsigned short* __restrict__ PQ,
                                              const int* __restrict__ ei,
                                              const unsigned short* __restrict__ w4f,
                                              const float* __restrict__ b4p,
                                              float* __restrict__ out) {
  const int t = threadIdx.x, w = t >> 6, l = t & 63, lr = l & 15, lh = l >> 4;
  const int m64 = probe64(ei);
  const int eb = blockIdx.x * 128 + w * 32;
  const int elA = eb + lr;
  const int elB = eb + 16 + lr;
  const int snA = ld_src(ei, m64, elA), dnA = ld_dst(ei, m64, elA);
  const int snB = ld_src(ei, m64, elB), dnB = ld_dst(ei, m64, elB);
  const unsigned short* PpA = PQ + (long)snA * 256;
  const unsigned short* QpA = PQ + (long)dnA * 256 + 128;
  const unsigned short* PpB = PQ + (long)snB * 256;
  const unsigned short* QpB = PQ + (long)dnB * 256 + 128;

  bf16x8 B4[3][4];
#pragma unroll
  for (int ci = 0; ci < 3; ++ci)
#pragma unroll
    for (int ks = 0; ks < 4; ++ks)
      B4[ci][ks] = *(const bf16x8*)(w4f + ((ci * 4 + ks) * 64 + l) * 8);

  f32x4 accA[3] = {};
  f32x4 accB[3] = {};
#pragma unroll
  for (int ks = 0; ks < 4; ++ks) {
    uint4 puA = *(const uint4*)(PpA + ks * 32 + lh * 8);
    uint4 quA = *(const uint4*)(QpA + ks * 32 + lh * 8);
    uint4 puB = *(const uint4*)(PpB + ks * 32 + lh * 8);
    uint4 quB = *(const uint4*)(QpB + ks * 32 + lh * 8);
    int4 a4A, a4B;
    a4A.x = pack2(fmaxf(lo_f(puA.x) + lo_f(quA.x), 0.f), fmaxf(hi_f(puA.x) + hi_f(quA.x), 0.f));
    a4A.y = pack2(fmaxf(lo_f(puA.y) + lo_f(quA.y), 0.f), fmaxf(hi_f(puA.y) + hi_f(quA.y), 0.f));
    a4A.z = pack2(fmaxf(lo_f(puA.z) + lo_f(quA.z), 0.f), fmaxf(hi_f(puA.z) + hi_f(quA.z), 0.f));
    a4A.w = pack2(fmaxf(lo_f(puA.w) + lo_f(quA.w), 0.f), fmaxf(hi_f(puA.w) + hi_f(quA.w), 0.f));
    a4B.x = pack2(fmaxf(lo_f(puB.x) + lo_f(quB.x), 0.f), fmaxf(hi_f(puB.x) + hi_f(quB.x), 0.f));
    a4B.y = pack2(fmaxf(lo_f(puB.y) + lo_f(quB.y), 0.f), fmaxf(hi_f(puB.y) + hi_f(quB.y), 0.f));
    a4B.z = pack2(fmaxf(lo_f(puB.z) + lo_f(quB.z), 0.f), fmaxf(hi_f(puB.z) + hi_f(quB.z), 0.f));
    a4B.w = pack2(fmaxf(lo_f(puB.w) + lo_f(quB.w), 0.f), fmaxf(hi_f(puB.w) + hi_f(quB.w), 0.f));
    bf16x8 aA = __builtin_bit_cast(bf16x8, a4A);
    bf16x8 aB = __builtin_bit_cast(bf16x8, a4B);
#pragma unroll
    for (int ci = 0; ci < 3; ++ci) {
      accA[ci] = __builtin_amdgcn_mfma_f32_16x16x32_bf16(aA, B4[ci][ks], accA[ci], 0, 0, 0);
      accB[ci] = __builtin_amdgcn_mfma_f32_16x16x32_bf16(aB, B4[ci][ks], accB[ci], 0, 0, 0);
    }
  }

  const bool val2 = lr < 8;
  const float bb0 = b4p[lr], bb1 = b4p[16 + lr], bb2 = b4p[32 + lr];
#pragma unroll
  for (int es = 0; es < 2; ++es) {
    float lg0[4], lg1[4], lg2[4];
#pragma unroll
    for (int r = 0; r < 4; ++r) {
      f32x4* ac = es ? accB : accA;
      lg0[r] = ac[0][r] + bb0;
      lg1[r] = ac[1][r] + bb1;
      lg2[r] = ac[2][r] + bb2;
    }
#pragma unroll
    for (int r = 0; r < 4; ++r) {
      float m = fmaxf(lg0[r], lg1[r]);
      if (val2) m = fmaxf(m, lg2[r]);
      m = fmaxf(m, __shfl_xor(m, 1, 64));
      m = fmaxf(m, __shfl_xor(m, 2, 64));
      m = fmaxf(m, __shfl_xor(m, 4, 64));
      m = fmaxf(m, __shfl_xor(m, 8, 64));
      float s = __expf(lg0[r] - m) + __expf(lg1[r] - m) + (val2 ? __expf(lg2[r] - m) : 0.f);
      s += __shfl_xor(s, 1, 64);
      s += __shfl_xor(s, 2, 64);
      s += __shfl_xor(s, 4, 64);
      s += __shfl_xor(s, 8, 64);
      float lse = m + __logf(s);
      long ob = (long)(eb + es * 16 + lh * 4 + r) * 40;
      out[ob + lr] = lg0[r] - lse;
      out[ob + 16 + lr] = lg1[r] - lse;
      if (val2) out[ob + 32 + lr] = lg2[r] - lse;
    }
  }
}

extern "C" void kernel_launch(void* const* d_in, const int* in_sizes, int n_in,
                              void* d_out, int out_size, void* d_ws, size_t ws_size,
                              hipStream_t stream) {
  const float* x = (const float*)d_in[0];
  const int* ei = (const int*)d_in[1];
  const float* W1 = (const float*)d_in[2];
  const float* b1 = (const float*)d_in[3];
  const float* W2 = (const float*)d_in[4];
  const float* b2 = (const float*)d_in[5];
  const float* W3 = (const float*)d_in[6];
  const float* b3 = (const float*)d_in[7];
  const float* W4 = (const float*)d_in[8];
  const float* b4 = (const float*)d_in[9];
  char* ws = (char*)d_ws;
  int* cnt = (int*)(ws + 0);
  unsigned short* pad = (unsigned short*)(ws + 200064);
  unsigned short* S = (unsigned short*)(ws + 13000192);  // PQ aliases S (dead after agg)
  unsigned short* Ypr = (unsigned short*)(ws + 38600192);
  unsigned short* w1f = (unsigned short*)(ws + 64200192);
  unsigned short* w2f = (unsigned short*)(ws + 64331264);
  unsigned short* w3f = (unsigned short*)(ws + 64396800);
  unsigned short* w4f = (unsigned short*)(ws + 64462336);
  float* b4p = (float*)(ws + 64474624);
  float* out = (float*)d_out;

  (void)hipMemsetAsync(ws, 0, 200064, stream);  // cnt
  k_prep_frags<<<537, 256, 0, stream>>>(W1, W2, W3, W4, b4, w1f, w2f, w3f, w4f, b4p);
  k_count_scatter<<<3125, 256, 0, stream>>>(ei, cnt, pad);
  k_sy<<<782, 512, 0, stream>>>(x, w1f, b1, S, Ypr);
  k_edge_agg<<<6250, 512, 0, stream>>>(S, Ypr, cnt, pad);
  k_pq<<<782, 256, 0, stream>>>(Ypr, S, w2f, b2, w3f, b3);
  k_head<<<6250, 256, 0, stream>>>(S, ei, w4f, b4p, out);
}